// Round 3
// baseline (3091.310 us; speedup 1.0000x reference)
//
#include <hip/hip_runtime.h>
#include <math.h>
#include <stdint.h>

// VQ-VAE vector quantizer (inference), MI355X / gfx950.
// N=32768 tokens, D=256, K=8192 codes. f32 path (no fp32 MFMA on CDNA4).
// Reference rounding replicated: d = fl(fl(S+e2) - 2*dot), argmin first-index.
// NOTE (numerics): S~256, e2<4e-6 => fl(S+e2)==S always; distances quantize to
// ulp(256)~3e-5 bins with ~27 codes/bin => argmin decided by bin membership.
// Sub-1e-8 dot-order differences vs XLA can flip boundary codes; exact index
// match is structurally impossible. Next lever (after f32 baseline validates):
// split-bf16 MFMA dot (hi*hi + hi*lo + lo*hi), ~5x faster, same error class.

#define N_TOK   32768
#define DIM     256
#define K_EMB   8192

// ---- workspace layout (bytes) ----
#define WS_S       0          // float[32768]    sum z^2 per token
#define WS_E2      131072     // float[8192]     sum e^2 per code
#define WS_PVAL    163840     // float[4*32768]  per-col-quarter best value
#define WS_PIDX    688128     // int[4*32768]    per-col-quarter best index
#define WS_CNT     1212416    // float[8192]     counts
#define WS_PART    1245184    // float[32768]    per-token loss partials
#define WS_ET      1376256    // float[8192*256] E transposed (optional)
#define WS_END_ET  9764864

__device__ __forceinline__ void gload_lds16(const float* g, float* l) {
  __builtin_amdgcn_global_load_lds(
      (const __attribute__((address_space(1))) void*)g,
      (__attribute__((address_space(3))) void*)l, 16, 0, 0);
}

__global__ void k_sumz(const float* __restrict__ z, float* __restrict__ S) {
  int t = blockIdx.x * blockDim.x + threadIdx.x;
  const float4* zp = (const float4*)(z + (size_t)t * DIM);
  float s = 0.0f;
  #pragma unroll 4
  for (int g = 0; g < DIM / 4; ++g) {
    float4 v = zp[g];
    s = __fadd_rn(s, __fmul_rn(v.x, v.x));
    s = __fadd_rn(s, __fmul_rn(v.y, v.y));
    s = __fadd_rn(s, __fmul_rn(v.z, v.z));
    s = __fadd_rn(s, __fmul_rn(v.w, v.w));
  }
  S[t] = s;
}

// 64 cols/block, 4 d-quarters/col. Quarter-split reordering vs reference is
// harmless: e2 is fully absorbed by fl(S+e2)==S (see header note).
__global__ void k_sume(const float* __restrict__ E, float* __restrict__ e2) {
  __shared__ float part[4][64];
  int c  = threadIdx.x & 63;
  int dq = threadIdx.x >> 6;
  int col = blockIdx.x * 64 + c;
  float s = 0.0f;
  #pragma unroll 4
  for (int d = dq * 64; d < dq * 64 + 64; ++d) {
    float v = E[(size_t)d * K_EMB + col];
    s = __fadd_rn(s, __fmul_rn(v, v));
  }
  part[dq][c] = s;
  __syncthreads();
  if (threadIdx.x < 64)
    e2[blockIdx.x * 64 + threadIdx.x] =
        __fadd_rn(__fadd_rn(part[0][threadIdx.x], part[1][threadIdx.x]),
                  __fadd_rn(part[2][threadIdx.x], part[3][threadIdx.x]));
}

// E[256][8192] -> ET[8192][256], 32x32 tiles, +1-pad LDS.
__global__ void k_transpose(const float* __restrict__ E, float* __restrict__ ET) {
  __shared__ float tile[32][33];
  int k0 = blockIdx.x * 32, d0 = blockIdx.y * 32;
  int lx = threadIdx.x, ly = threadIdx.y;  // 32 x 8
  #pragma unroll
  for (int r = 0; r < 32; r += 8)
    tile[ly + r][lx] = E[(size_t)(d0 + ly + r) * K_EMB + k0 + lx];
  __syncthreads();
  #pragma unroll
  for (int r = 0; r < 32; r += 8)
    ET[(size_t)(k0 + ly + r) * DIM + d0 + lx] = tile[lx][ly + r];
}

// ---- fused distance-GEMM + argmin ----
// 16x16 per-thread tile: per CU per d-iter, VALU 512 cyc vs LDS ~384 cyc
// (b128 @ ~85B/cyc) -> VALU-bound with 25% LDS slack. BM=BN=256, BK=16,
// 64KB LDS double-buffered, 1 block/CU (VGPR-bound: ~400 regs, 1 wave/SIMD;
// 256 independent FMA chains give the ILP to keep the pipe full).
// Block covers 256 rows x 2048 cols (col-quarter), grid=512 -> 2 rounds/CU.
#define BM 256
#define BN 256
#define BK 16
#define NCT 8
#define COLS_PB (NCT * BN)
#define KSTEPS (DIM / BK)       // 16
#define NSTEP  (NCT * KSTEPS)   // 128

__launch_bounds__(256, 1)
__global__ void k_dist(const float* __restrict__ z, const float* __restrict__ E,
                       const float* __restrict__ S, const float* __restrict__ e2,
                       float* __restrict__ pval, int* __restrict__ pidx) {
  // zt: [buf][d][row] transposed (reads: 4 addrs/wave, conflict-free;
  //     staging b32 writes 4-way -- ~2% of budget). et: [buf][d][col] natural
  //     (reads 2-way = free), staged direct via global_load_lds (wave-uniform
  //     base + lane*16 matches layout exactly; no pe regs, no LDS writes).
  __shared__ __align__(16) float smem[2 * BK * BM + 2 * BK * BN];  // 64 KB
  float* zt = smem;
  float* et = smem + 2 * BK * BM;

  const int tid = threadIdx.x;
  const int tx  = tid & 15;     // col group
  const int ty  = tid >> 4;     // row group
  const int wv  = tid >> 6;     // wave 0..3
  const int ln  = tid & 63;     // lane
  const int rowblk = blockIdx.x >> 2;
  const int colq   = blockIdx.x & 3;
  const int row0    = rowblk * BM;
  const int colbase = colq * COLS_PB;

  float acc[16][16];
  #pragma unroll
  for (int i = 0; i < 16; ++i)
    #pragma unroll
    for (int j = 0; j < 16; ++j) acc[i][j] = 0.0f;

  float best[16];
  int   bidx[16];
  #pragma unroll
  for (int i = 0; i < 16; ++i) { best[i] = 3.402823466e38f; bidx[i] = 0; }

  float Sreg[16];
  #pragma unroll
  for (int i = 0; i < 16; ++i)
    Sreg[i] = S[row0 + (i >> 2) * 64 + ty * 4 + (i & 3)];

  float4 pz[4];

  // async E -> LDS: wave wv stages rows {wv, 4+wv, 8+wv, 12+wv} of the d-tile;
  // each wave-instr writes one contiguous 1KB et row (lane*16 dest, lane*4 src).
  auto LOADE = [&](int gs) {
    int ks = gs & (KSTEPS - 1), ct = gs >> 4;
    const float* gsrc = E + (size_t)(ks * BK) * K_EMB + colbase + ct * BN + ln * 4;
    float* lb = et + (gs & 1) * (BK * BN);
    #pragma unroll
    for (int it = 0; it < 4; ++it) {
      int dd = it * 4 + wv;
      gload_lds16(gsrc + (size_t)dd * K_EMB, lb + dd * BN);
    }
  };
  auto LOADZ = [&](int gs) {
    int d0 = (gs & (KSTEPS - 1)) * BK;
    #pragma unroll
    for (int it = 0; it < 4; ++it) {
      int l = it * 256 + tid;
      pz[it] = *(const float4*)&z[(size_t)(row0 + (l >> 2)) * DIM + d0 + (l & 3) * 4];
    }
  };
  auto STOREZ = [&](int b) {
    float* zb = zt + b * (BK * BM);
    #pragma unroll
    for (int it = 0; it < 4; ++it) {
      int l = it * 256 + tid;
      int zrow = l >> 2, zdg = l & 3;
      zb[(zdg * 4 + 0) * BM + zrow] = pz[it].x;
      zb[(zdg * 4 + 1) * BM + zrow] = pz[it].y;
      zb[(zdg * 4 + 2) * BM + zrow] = pz[it].z;
      zb[(zdg * 4 + 3) * BM + zrow] = pz[it].w;
    }
  };

  LOADE(0); LOADZ(0); STOREZ(0);
  __syncthreads();  // drains vmcnt -> E tile 0 resident

  for (int gs = 0; gs < NSTEP; ++gs) {
    const int buf = gs & 1;
    // prefetch next tile: E async into buf^1 (safe: last reads of buf^1 ended
    // before previous barrier), z into regs.
    if (gs + 1 < NSTEP) { LOADE(gs + 1); LOADZ(gs + 1); }

    const float* zb = zt + buf * (BK * BM);
    const float* eb = et + buf * (BK * BN);
    #pragma unroll 2
    for (int d = 0; d < BK; ++d) {
      float zr[16], ec[16];
      #pragma unroll
      for (int g = 0; g < 4; ++g) {
        float4 v = *(const float4*)&zb[d * BM + g * 64 + ty * 4];
        zr[g * 4 + 0] = v.x; zr[g * 4 + 1] = v.y;
        zr[g * 4 + 2] = v.z; zr[g * 4 + 3] = v.w;
        float4 w = *(const float4*)&eb[d * BN + g * 64 + tx * 4];
        ec[g * 4 + 0] = w.x; ec[g * 4 + 1] = w.y;
        ec[g * 4 + 2] = w.z; ec[g * 4 + 3] = w.w;
      }
      #pragma unroll
      for (int i = 0; i < 16; ++i)
        #pragma unroll
        for (int j = 0; j < 16; ++j)
          acc[i][j] = fmaf(zr[i], ec[j], acc[i][j]);
    }

    // per col-tile: reference-exact d = fl(fl(S+e2) - 2*dot), strict-< argmin
    if ((gs & (KSTEPS - 1)) == KSTEPS - 1) {
      int col0c = colbase + (gs >> 4) * BN;
      float e2r[16];
      #pragma unroll
      for (int j = 0; j < 16; ++j)
        e2r[j] = e2[col0c + (j >> 2) * 64 + tx * 4 + (j & 3)];
      #pragma unroll
      for (int i = 0; i < 16; ++i) {
        #pragma unroll
        for (int j = 0; j < 16; ++j) {  // j ascending == index ascending
          float t1  = __fadd_rn(Sreg[i], e2r[j]);
          float val = __fsub_rn(t1, __fmul_rn(2.0f, acc[i][j]));
          int cidx  = col0c + (j >> 2) * 64 + tx * 4 + (j & 3);
          if (val < best[i]) { best[i] = val; bidx[i] = cidx; }
          acc[i][j] = 0.0f;
        }
      }
    }

    if (gs + 1 < NSTEP) STOREZ(buf ^ 1);  // writes buf^1; readers are on buf
    __syncthreads();  // one barrier/iter: drains gload_lds + orders buffers
  }

  // cross-thread argmin per row (16 tx candidates), lexicographic (val, idx)
  float* redv = smem;
  int*   redi = (int*)(smem + BM * 16);
  #pragma unroll
  for (int i = 0; i < 16; ++i) {
    int r = (i >> 2) * 64 + ty * 4 + (i & 3);
    redv[r * 16 + tx] = best[i];
    redi[r * 16 + tx] = bidx[i];
  }
  __syncthreads();
  {
    float bv = redv[tid * 16];
    int   bi = redi[tid * 16];
    #pragma unroll
    for (int u = 1; u < 16; ++u) {
      float v = redv[tid * 16 + u];
      int  ii = redi[tid * 16 + u];
      if (v < bv || (v == bv && ii < bi)) { bv = v; bi = ii; }
    }
    pval[(size_t)colq * N_TOK + row0 + tid] = bv;
    pidx[(size_t)colq * N_TOK + row0 + tid] = bi;
  }
}

__global__ void k_out(const float* __restrict__ z, const float* __restrict__ E,
                      const float* __restrict__ ET, int useET,
                      const float* __restrict__ pval, const int* __restrict__ pidx,
                      float* __restrict__ out, float* __restrict__ counts,
                      float* __restrict__ partials) {
  int n = blockIdx.x;
  int t = threadIdx.x;
  float bv = pval[n];
  int   bi = pidx[n];
  #pragma unroll
  for (int q = 1; q < 4; ++q) {  // quarters ascend in index; strict < keeps lowest
    float v = pval[(size_t)q * N_TOK + n];
    int  ii = pidx[(size_t)q * N_TOK + n];
    if (v < bv || (v == bv && ii < bi)) { bv = v; bi = ii; }
  }
  int idx = bi;

  float q  = useET ? ET[(size_t)idx * DIM + t]     // coalesced row gather
                   : E[(size_t)t * K_EMB + idx];   // fallback column gather
  float zz = z[(size_t)n * DIM + t];
  float dd = __fsub_rn(q, zz);
  out[(size_t)n * DIM + t] = __fadd_rn(zz, dd);  // straight-through: z + (q - z)
  float sq = __fmul_rn(dd, dd);

  #pragma unroll
  for (int o = 32; o > 0; o >>= 1) sq += __shfl_down(sq, o);
  __shared__ float wsum[4];
  if ((t & 63) == 0) wsum[t >> 6] = sq;
  __syncthreads();
  if (t == 0) {
    partials[n] = ((wsum[0] + wsum[1]) + (wsum[2] + wsum[3]));
    atomicAdd(&counts[idx], 1.0f);
    out[(size_t)N_TOK * DIM + n] = (float)idx;
  }
}

__global__ void k_final(const float* __restrict__ partials,
                        const float* __restrict__ counts,
                        float* __restrict__ out) {
  __shared__ double sd[256];
  int t = threadIdx.x;
  double s = 0.0;
  for (int i = t; i < N_TOK; i += 256) s += (double)partials[i];
  sd[t] = s;
  __syncthreads();
  for (int o = 128; o > 0; o >>= 1) { if (t < o) sd[t] += sd[t + o]; __syncthreads(); }
  double totalLoss = sd[0];
  __syncthreads();
  double s2 = 0.0;
  for (int k = t; k < K_EMB; k += 256) {
    float p = counts[k] * (1.0f / (float)N_TOK);
    s2 += (double)(p * logf(p + 1e-10f));
  }
  sd[t] = s2;
  __syncthreads();
  for (int o = 128; o > 0; o >>= 1) { if (t < o) sd[t] += sd[t + o]; __syncthreads(); }
  if (t == 0) {
    const size_t base = (size_t)N_TOK * DIM + N_TOK;  // 8421376
    out[base + 0] = 0.0f;
    out[base + 1] = 0.25f * (float)(totalLoss / (double)(N_TOK * DIM));
    out[base + 2] = expf(-(float)sd[0]);
  }
}

extern "C" void kernel_launch(void* const* d_in, const int* in_sizes, int n_in,
                              void* d_out, int out_size, void* d_ws, size_t ws_size,
                              hipStream_t stream) {
  const float* z = (const float*)d_in[0];
  const float* E = (const float*)d_in[1];
  float* out = (float*)d_out;
  char* w = (char*)d_ws;
  float* S        = (float*)(w + WS_S);
  float* e2       = (float*)(w + WS_E2);
  float* pval     = (float*)(w + WS_PVAL);
  int*   pidx     = (int*)(w + WS_PIDX);
  float* counts   = (float*)(w + WS_CNT);
  float* partials = (float*)(w + WS_PART);
  float* ET       = (float*)(w + WS_ET);
  const int useET = (ws_size >= (size_t)WS_END_ET) ? 1 : 0;  // constant across calls

  hipMemsetAsync(w + WS_CNT, 0, K_EMB * sizeof(float), stream);
  k_sumz<<<N_TOK / 256, 256, 0, stream>>>(z, S);
  k_sume<<<K_EMB / 64, 256, 0, stream>>>(E, e2);
  if (useET) {
    dim3 tg(K_EMB / 32, DIM / 32);
    k_transpose<<<tg, dim3(32, 8), 0, stream>>>(E, ET);
  }
  k_dist<<<512, 256, 0, stream>>>(z, E, S, e2, pval, pidx);
  k_out<<<N_TOK, 256, 0, stream>>>(z, E, ET, useET, pval, pidx, out, counts, partials);
  k_final<<<1, 256, 0, stream>>>(partials, counts, out);
}

// Round 4
// 1689.950 us; speedup vs baseline: 1.8292x; 1.8292x over previous
//
#include <hip/hip_runtime.h>
#include <math.h>
#include <stdint.h>

// VQ-VAE vector quantizer (inference), MI355X / gfx950.
// N=32768 tokens, D=256, K=8192 codes. f32 path (no fp32 MFMA on CDNA4).
// Round-3 result: absmax=0.0 (fmaf-chain == XLA argmin exactly), but 16x16
// acc tile spilled to AGPRs (VGPR=224 < 256 accs; accvgpr moves ~3x VALU).
// Round-4 fix: 8x16 tile (128 acc, ~190 regs), z pre-transposed so BOTH
// tiles stage via global_load_lds (no scatter writes), 2 blocks/CU.

#define N_TOK   32768
#define DIM     256
#define K_EMB   8192

// ---- workspace layout (bytes) ----
#define WS_S       0          // float[32768]
#define WS_E2      131072     // float[8192]
#define WS_PVAL    163840     // float[2*32768] per-col-half best value
#define WS_PIDX    425984     // int[2*32768]   per-col-half best index
#define WS_CNT     688128     // float[8192]
#define WS_PART    720896     // float[32768]
#define WS_ZT      851968     // float[256*32768] z transposed (required if fits)
#define WS_END_ZT  34406400
#define WS_ET      34406400   // float[8192*256]  E transposed (optional, k_out)
#define WS_END_ET  42795008

__device__ __forceinline__ void gload_lds16(const float* g, float* l) {
  __builtin_amdgcn_global_load_lds(
      (const __attribute__((address_space(1))) void*)g,
      (__attribute__((address_space(3))) void*)l, 16, 0, 0);
}

__global__ void k_sumz(const float* __restrict__ z, float* __restrict__ S) {
  int t = blockIdx.x * blockDim.x + threadIdx.x;
  const float4* zp = (const float4*)(z + (size_t)t * DIM);
  float s = 0.0f;
  #pragma unroll 4
  for (int g = 0; g < DIM / 4; ++g) {
    float4 v = zp[g];
    s = __fadd_rn(s, __fmul_rn(v.x, v.x));
    s = __fadd_rn(s, __fmul_rn(v.y, v.y));
    s = __fadd_rn(s, __fmul_rn(v.z, v.z));
    s = __fadd_rn(s, __fmul_rn(v.w, v.w));
  }
  S[t] = s;
}

// e2 exact value is non-critical: fl(S+e2)==S since S~256, e2<4e-6.
__global__ void k_sume(const float* __restrict__ E, float* __restrict__ e2) {
  __shared__ float part[4][64];
  int c  = threadIdx.x & 63;
  int dq = threadIdx.x >> 6;
  int col = blockIdx.x * 64 + c;
  float s = 0.0f;
  #pragma unroll 4
  for (int d = dq * 64; d < dq * 64 + 64; ++d) {
    float v = E[(size_t)d * K_EMB + col];
    s = __fadd_rn(s, __fmul_rn(v, v));
  }
  part[dq][c] = s;
  __syncthreads();
  if (threadIdx.x < 64)
    e2[blockIdx.x * 64 + threadIdx.x] =
        __fadd_rn(__fadd_rn(part[0][threadIdx.x], part[1][threadIdx.x]),
                  __fadd_rn(part[2][threadIdx.x], part[3][threadIdx.x]));
}

// z[32768][256] -> zT[256][32768], 32x32 tiles, +1-pad LDS. ~15us.
__global__ void k_transpose_z(const float* __restrict__ z, float* __restrict__ zT) {
  __shared__ float tile[32][33];
  int n0 = blockIdx.x * 32, d0 = blockIdx.y * 32;
  int lx = threadIdx.x, ly = threadIdx.y;  // 32 x 8
  #pragma unroll
  for (int r = 0; r < 32; r += 8)
    tile[ly + r][lx] = z[(size_t)(n0 + ly + r) * DIM + d0 + lx];
  __syncthreads();
  #pragma unroll
  for (int r = 0; r < 32; r += 8)
    zT[(size_t)(d0 + ly + r) * N_TOK + n0 + lx] = tile[lx][ly + r];
}

// E[256][8192] -> ET[8192][256] for k_out's coalesced gather.
__global__ void k_transpose_e(const float* __restrict__ E, float* __restrict__ ET) {
  __shared__ float tile[32][33];
  int k0 = blockIdx.x * 32, d0 = blockIdx.y * 32;
  int lx = threadIdx.x, ly = threadIdx.y;
  #pragma unroll
  for (int r = 0; r < 32; r += 8)
    tile[ly + r][lx] = E[(size_t)(d0 + ly + r) * K_EMB + k0 + lx];
  __syncthreads();
  #pragma unroll
  for (int r = 0; r < 32; r += 8)
    ET[(size_t)(k0 + ly + r) * DIM + d0 + lx] = tile[lx][ly + r];
}

// ---- fused distance-GEMM + argmin ----
// 8x16 per-thread tile, BM=128, BN=256, BK=16. Per CU/d-iter (2 blocks):
// VALU 512 cyc vs LDS ~576 cyc -> mildly LDS-bound, ideal ~983us.
// 48KB LDS double-buffered; ~190 regs -> 2 waves/SIMD; grid 512 = 2 blocks/CU.
#define BM 128
#define BN 256
#define BK 16
#define KSTEPS 16
#define NCT 16                  // 16 col-tiles x 256 = 4096 cols (half of K)
#define NSTEP (NCT * KSTEPS)    // 256

template<bool USE_ZT>
__launch_bounds__(256, 2)
__global__ void k_dist(const float* __restrict__ zsrc, const float* __restrict__ E,
                       const float* __restrict__ S, const float* __restrict__ e2,
                       float* __restrict__ pval, int* __restrict__ pidx) {
  // zt: [buf][d][row] (reads: 4 distinct 16B addrs/wave + broadcast = conflict-free)
  // et: [buf][d][col] (reads 2-way = free). Both staged via global_load_lds
  // when USE_ZT (wave-uniform dest + lane*16 matches the linear layouts).
  __shared__ __align__(16) float smem[2 * BK * BM + 2 * BK * BN];  // 48 KB
  float* zt = smem;
  float* et = smem + 2 * BK * BM;

  const int tid = threadIdx.x;
  const int tx  = tid & 15;     // col group
  const int ty  = tid >> 4;     // row group
  const int wv  = tid >> 6;     // wave 0..3
  const int ln  = tid & 63;     // lane
  const int rowblk = blockIdx.x >> 1;
  const int half   = blockIdx.x & 1;
  const int row0    = rowblk * BM;
  const int colbase = half * (NCT * BN);

  float acc[8][16];
  #pragma unroll
  for (int i = 0; i < 8; ++i)
    #pragma unroll
    for (int j = 0; j < 16; ++j) acc[i][j] = 0.0f;

  float best[8];
  int   bidx[8];
  #pragma unroll
  for (int i = 0; i < 8; ++i) { best[i] = 3.402823466e38f; bidx[i] = 0; }

  float Sreg[8];
  #pragma unroll
  for (int i = 0; i < 8; ++i)
    Sreg[i] = S[row0 + (i >> 2) * 64 + ty * 4 + (i & 3)];

  // E tile: 16 d-rows x 1KB; wave wv stages d-rows {wv,4+wv,8+wv,12+wv}.
  auto LOADE = [&](int gs) {
    int ks = gs & (KSTEPS - 1), ct = gs >> 4;
    const float* gsrc = E + (size_t)(ks * BK) * K_EMB + colbase + ct * BN + ln * 4;
    float* lb = et + (gs & 1) * (BK * BN);
    #pragma unroll
    for (int it = 0; it < 4; ++it) {
      int dd = it * 4 + wv;
      gload_lds16(gsrc + (size_t)dd * K_EMB, lb + dd * BN);
    }
  };
  // zT tile: 16 d-rows x 512B; one 1KB wave-instr covers a d-row PAIR
  // (lanes 0-31 -> d-row 2p, lanes 32-63 -> d-row 2p+1). 8 instrs, 2/wave.
  auto LOADZT = [&](int gs) {
    int d0 = (gs & (KSTEPS - 1)) * BK;
    float* lb = zt + (gs & 1) * (BK * BM);
    int h = ln >> 5, j = ln & 31;
    #pragma unroll
    for (int it = 0; it < 2; ++it) {
      int p = it * 4 + wv;
      gload_lds16(zsrc + (size_t)(d0 + 2 * p + h) * N_TOK + row0 + j * 4,
                  lb + (2 * p) * BM);
    }
  };
  // fallback (no zT buffer): reg-stage + b32 transpose scatter (4-way, ~6%)
  float4 pz[2];
  auto LOADZG = [&](int gs) {
    int d0 = (gs & (KSTEPS - 1)) * BK;
    #pragma unroll
    for (int it = 0; it < 2; ++it) {
      int l = it * 256 + tid;
      pz[it] = *(const float4*)&zsrc[(size_t)(row0 + (l >> 2)) * DIM + d0 + (l & 3) * 4];
    }
  };
  auto STOREZ = [&](int b) {
    float* zb = zt + b * (BK * BM);
    #pragma unroll
    for (int it = 0; it < 2; ++it) {
      int l = it * 256 + tid;
      int zrow = l >> 2, zdg = l & 3;
      zb[(zdg * 4 + 0) * BM + zrow] = pz[it].x;
      zb[(zdg * 4 + 1) * BM + zrow] = pz[it].y;
      zb[(zdg * 4 + 2) * BM + zrow] = pz[it].z;
      zb[(zdg * 4 + 3) * BM + zrow] = pz[it].w;
    }
  };

  LOADE(0);
  if (USE_ZT) { LOADZT(0); } else { LOADZG(0); STOREZ(0); }
  __syncthreads();  // drains vmcnt -> tile 0 resident

  for (int gs = 0; gs < NSTEP; ++gs) {
    const int buf = gs & 1;
    if (gs + 1 < NSTEP) {        // prefetch into buf^1 (last read 2 barriers ago)
      LOADE(gs + 1);
      if (USE_ZT) LOADZT(gs + 1); else LOADZG(gs + 1);
    }

    const float* zb = zt + buf * (BK * BM);
    const float* eb = et + buf * (BK * BN);
    #pragma unroll 4
    for (int d = 0; d < BK; ++d) {
      float zr[8], ec[16];
      {
        float4 a0 = *(const float4*)&zb[d * BM + ty * 4];
        float4 a1 = *(const float4*)&zb[d * BM + 64 + ty * 4];
        zr[0] = a0.x; zr[1] = a0.y; zr[2] = a0.z; zr[3] = a0.w;
        zr[4] = a1.x; zr[5] = a1.y; zr[6] = a1.z; zr[7] = a1.w;
      }
      #pragma unroll
      for (int g = 0; g < 4; ++g) {
        float4 w = *(const float4*)&eb[d * BN + g * 64 + tx * 4];
        ec[g * 4 + 0] = w.x; ec[g * 4 + 1] = w.y;
        ec[g * 4 + 2] = w.z; ec[g * 4 + 3] = w.w;
      }
      #pragma unroll
      for (int i = 0; i < 8; ++i)
        #pragma unroll
        for (int j = 0; j < 16; ++j)
          acc[i][j] = fmaf(zr[i], ec[j], acc[i][j]);
    }

    // per col-tile: reference-exact d = fl(fl(S+e2) - 2*dot), strict-< argmin
    if ((gs & (KSTEPS - 1)) == KSTEPS - 1) {
      int col0c = colbase + (gs >> 4) * BN;
      float e2r[16];
      #pragma unroll
      for (int j = 0; j < 16; ++j)
        e2r[j] = e2[col0c + (j >> 2) * 64 + tx * 4 + (j & 3)];
      #pragma unroll
      for (int i = 0; i < 8; ++i) {
        #pragma unroll
        for (int j = 0; j < 16; ++j) {  // j ascending == index ascending
          float t1  = __fadd_rn(Sreg[i], e2r[j]);
          float val = __fsub_rn(t1, __fmul_rn(2.0f, acc[i][j]));
          int cidx  = col0c + (j >> 2) * 64 + tx * 4 + (j & 3);
          if (val < best[i]) { best[i] = val; bidx[i] = cidx; }
          acc[i][j] = 0.0f;
        }
      }
    }

    if (!USE_ZT && gs + 1 < NSTEP) STOREZ(buf ^ 1);
    __syncthreads();  // one barrier/iter: drains gload_lds + orders buffers
  }

  // per-row argmin across 16 tx candidates, lexicographic (val, idx)
  float* redv = smem;
  int*   redi = (int*)(smem + BM * 16);
  #pragma unroll
  for (int i = 0; i < 8; ++i) {
    int r = (i >> 2) * 64 + ty * 4 + (i & 3);
    redv[r * 16 + tx] = best[i];
    redi[r * 16 + tx] = bidx[i];
  }
  __syncthreads();
  if (tid < BM) {
    float bv = redv[tid * 16];
    int   bi = redi[tid * 16];
    #pragma unroll
    for (int u = 1; u < 16; ++u) {
      float v = redv[tid * 16 + u];
      int  ii = redi[tid * 16 + u];
      if (v < bv || (v == bv && ii < bi)) { bv = v; bi = ii; }
    }
    pval[(size_t)half * N_TOK + row0 + tid] = bv;
    pidx[(size_t)half * N_TOK + row0 + tid] = bi;
  }
}

__global__ void k_out(const float* __restrict__ z, const float* __restrict__ E,
                      const float* __restrict__ ET, int useET,
                      const float* __restrict__ pval, const int* __restrict__ pidx,
                      float* __restrict__ out, float* __restrict__ counts,
                      float* __restrict__ partials) {
  int n = blockIdx.x;
  int t = threadIdx.x;
  float bv = pval[n];
  int   bi = pidx[n];
  {  // half 1 (indices all larger; strict < keeps lowest)
    float v = pval[(size_t)N_TOK + n];
    int  ii = pidx[(size_t)N_TOK + n];
    if (v < bv || (v == bv && ii < bi)) { bv = v; bi = ii; }
  }
  int idx = bi;

  float q  = useET ? ET[(size_t)idx * DIM + t]
                   : E[(size_t)t * K_EMB + idx];
  float zz = z[(size_t)n * DIM + t];
  float dd = __fsub_rn(q, zz);
  out[(size_t)n * DIM + t] = __fadd_rn(zz, dd);  // straight-through: z + (q - z)
  float sq = __fmul_rn(dd, dd);

  #pragma unroll
  for (int o = 32; o > 0; o >>= 1) sq += __shfl_down(sq, o);
  __shared__ float wsum[4];
  if ((t & 63) == 0) wsum[t >> 6] = sq;
  __syncthreads();
  if (t == 0) {
    partials[n] = ((wsum[0] + wsum[1]) + (wsum[2] + wsum[3]));
    atomicAdd(&counts[idx], 1.0f);
    out[(size_t)N_TOK * DIM + n] = (float)idx;
  }
}

__global__ void k_final(const float* __restrict__ partials,
                        const float* __restrict__ counts,
                        float* __restrict__ out) {
  __shared__ double sd[256];
  int t = threadIdx.x;
  double s = 0.0;
  for (int i = t; i < N_TOK; i += 256) s += (double)partials[i];
  sd[t] = s;
  __syncthreads();
  for (int o = 128; o > 0; o >>= 1) { if (t < o) sd[t] += sd[t + o]; __syncthreads(); }
  double totalLoss = sd[0];
  __syncthreads();
  double s2 = 0.0;
  for (int k = t; k < K_EMB; k += 256) {
    float p = counts[k] * (1.0f / (float)N_TOK);
    s2 += (double)(p * logf(p + 1e-10f));
  }
  sd[t] = s2;
  __syncthreads();
  for (int o = 128; o > 0; o >>= 1) { if (t < o) sd[t] += sd[t + o]; __syncthreads(); }
  if (t == 0) {
    const size_t base = (size_t)N_TOK * DIM + N_TOK;  // 8421376
    out[base + 0] = 0.0f;
    out[base + 1] = 0.25f * (float)(totalLoss / (double)(N_TOK * DIM));
    out[base + 2] = expf(-(float)sd[0]);
  }
}

extern "C" void kernel_launch(void* const* d_in, const int* in_sizes, int n_in,
                              void* d_out, int out_size, void* d_ws, size_t ws_size,
                              hipStream_t stream) {
  const float* z = (const float*)d_in[0];
  const float* E = (const float*)d_in[1];
  float* out = (float*)d_out;
  char* w = (char*)d_ws;
  float* S        = (float*)(w + WS_S);
  float* e2       = (float*)(w + WS_E2);
  float* pval     = (float*)(w + WS_PVAL);
  int*   pidx     = (int*)(w + WS_PIDX);
  float* counts   = (float*)(w + WS_CNT);
  float* partials = (float*)(w + WS_PART);
  float* zT       = (float*)(w + WS_ZT);
  float* ET       = (float*)(w + WS_ET);
  const int useZT = (ws_size >= (size_t)WS_END_ZT) ? 1 : 0;
  const int useET = (ws_size >= (size_t)WS_END_ET) ? 1 : 0;

  hipMemsetAsync(w + WS_CNT, 0, K_EMB * sizeof(float), stream);
  k_sumz<<<N_TOK / 256, 256, 0, stream>>>(z, S);
  k_sume<<<K_EMB / 64, 256, 0, stream>>>(E, e2);
  if (useZT)
    k_transpose_z<<<dim3(N_TOK / 32, DIM / 32), dim3(32, 8), 0, stream>>>(z, zT);
  if (useET)
    k_transpose_e<<<dim3(K_EMB / 32, DIM / 32), dim3(32, 8), 0, stream>>>(E, ET);
  if (useZT)
    k_dist<true><<<512, 256, 0, stream>>>(zT, E, S, e2, pval, pidx);
  else
    k_dist<false><<<512, 256, 0, stream>>>(z, E, S, e2, pval, pidx);
  k_out<<<N_TOK, 256, 0, stream>>>(z, E, ET, useET, pval, pidx, out, counts, partials);
  k_final<<<1, 256, 0, stream>>>(partials, counts, out);
}